// Round 8
// baseline (315.306 us; speedup 1.0000x reference)
//
#include <hip/hip_runtime.h>
#include <hip/hip_bf16.h>
#include <cmath>

typedef __bf16 bf16_t;
typedef __bf16 bf16x8 __attribute__((ext_vector_type(8)));
typedef float f32x4 __attribute__((ext_vector_type(4)));

#define MFMA16(A, B, C) __builtin_amdgcn_mfma_f32_16x16x32_bf16(A, B, C, 0, 0, 0)

// ---------------------------------------------------------------------------
// fp32 -> bf16 elementwise (x pre-convert), 8 elems/thread
// ---------------------------------------------------------------------------
__global__ __launch_bounds__(256) void f32_to_bf16(
    const float* __restrict__ src, bf16_t* __restrict__ dst) {
  const size_t i = (size_t)blockIdx.x * 256 + threadIdx.x;
  const float4 a0 = ((const float4*)src)[i * 2];
  const float4 a1 = ((const float4*)src)[i * 2 + 1];
  bf16x8 v = {(bf16_t)a0.x, (bf16_t)a0.y, (bf16_t)a0.z, (bf16_t)a0.w,
              (bf16_t)a1.x, (bf16_t)a1.y, (bf16_t)a1.z, (bf16_t)a1.w};
  ((bf16x8*)dst)[i] = v;
}

// ---------------------------------------------------------------------------
// Transpose fp32 src[R][C] -> bf16 dst[C][R]  (R, C multiples of 32)
// ---------------------------------------------------------------------------
__global__ __launch_bounds__(256) void transpose_f32_to_bf16(
    const float* __restrict__ src, bf16_t* __restrict__ dst, int R, int C) {
  __shared__ bf16_t tile[32][33];
  const int c0 = blockIdx.x * 32, r0 = blockIdx.y * 32;
  const int tr = threadIdx.x >> 5;   // 0..7
  const int tc = threadIdx.x & 31;   // 0..31
#pragma unroll
  for (int i = 0; i < 32; i += 8)
    tile[tr + i][tc] = (bf16_t)src[(size_t)(r0 + tr + i) * C + (c0 + tc)];
  __syncthreads();
#pragma unroll
  for (int i = 0; i < 32; i += 8)
    dst[(size_t)(c0 + tr + i) * R + (r0 + tc)] = tile[tc][tr + i];
}

// ---------------------------------------------------------------------------
// Register-direct GEMM  out = A[M][K] * BT[N][K]^T + bias[N]  (bf16, fp32 acc)
// NO LDS, NO barriers: each wave loads its MFMA fragments straight from
// global (dwordx4 per lane) with explicit ping-pong prefetch of the next
// K-slice. Removes the structural s_waitcnt vmcnt(0)-before-s_barrier stall
// (m97 plateau); per-wave vmcnt scheduling + 12 waves/CU hide load latency.
// A rows are L1-shared across the wc wave pair; BT rows are L2-resident.
// QKV=true:  scatter bf16 into q [B*H][T][64], k [B*H][T][64], vt [B*H][64][T]
// QKV=false: write fp32 of[M][N].
// ---------------------------------------------------------------------------
template <bool QKV>
__global__ __launch_bounds__(256, 3) void gemm_bt(
    const bf16_t* __restrict__ A, const bf16_t* __restrict__ BT,
    const float* __restrict__ bias,
    bf16_t* __restrict__ o0, bf16_t* __restrict__ o1, bf16_t* __restrict__ o2,
    float* __restrict__ of, int M, int N, int K) {
  const int tid = threadIdx.x;
  const int wave = tid >> 6, lane = tid & 63;
  const int wr = wave >> 1, wc = wave & 1;
  const int quad = lane >> 4, l16 = lane & 15;
  const int mt = blockIdx.y, nt = blockIdx.x;

  const int m_base = mt * 128 + wr * 64;
  const int n_base = nt * 128 + wc * 64;

  const bf16_t* Ap[4];
  const bf16_t* Bp[4];
#pragma unroll
  for (int i = 0; i < 4; ++i) {
    Ap[i] = A + (size_t)(m_base + i * 16 + l16) * K + quad * 8;
    Bp[i] = BT + (size_t)(n_base + i * 16 + l16) * K + quad * 8;
  }

  f32x4 acc[4][4] = {};
  bf16x8 a0[4], b0[4], a1[4], b1[4];
#pragma unroll
  for (int i = 0; i < 4; ++i) {
    a0[i] = *(const bf16x8*)(Ap[i]);
    b0[i] = *(const bf16x8*)(Bp[i]);
  }

  const int NIT = K / 32;  // 24
  for (int k = 0; k < NIT - 1; ++k) {
    const int off = (k + 1) * 32;
    // prefetch next K-slice (independent of the MFMAs below)
#pragma unroll
    for (int i = 0; i < 4; ++i) {
      a1[i] = *(const bf16x8*)(Ap[i] + off);
      b1[i] = *(const bf16x8*)(Bp[i] + off);
    }
#pragma unroll
    for (int mi = 0; mi < 4; ++mi)
#pragma unroll
      for (int ni = 0; ni < 4; ++ni)
        acc[mi][ni] = MFMA16(a0[mi], b0[ni], acc[mi][ni]);
#pragma unroll
    for (int i = 0; i < 4; ++i) {
      a0[i] = a1[i];
      b0[i] = b1[i];
    }
  }
#pragma unroll
  for (int mi = 0; mi < 4; ++mi)
#pragma unroll
    for (int ni = 0; ni < 4; ++ni)
      acc[mi][ni] = MFMA16(a0[mi], b0[ni], acc[mi][ni]);

  // Epilogue. C/D layout: col = l16 (n), row = quad*4 + r (m).
#pragma unroll
  for (int ni = 0; ni < 4; ++ni) {
    const int n = n_base + ni * 16 + l16;
    const float bv = bias[n];
    int which = 0, h = 0, d = 0;
    if (QKV) {
      which = n / 768;
      const int c = n - which * 768;
      h = c >> 6;
      d = c & 63;
    }
#pragma unroll
    for (int mi = 0; mi < 4; ++mi) {
#pragma unroll
      for (int r = 0; r < 4; ++r) {
        const int m = m_base + mi * 16 + quad * 4 + r;
        const float val = acc[mi][ni][r] + bv;
        if (QKV) {
          const bf16_t bw = (bf16_t)val;
          const int b = m >> 10, t = m & 1023;
          const size_t bh = (size_t)(b * 12 + h);
          if (which == 0)
            o0[(bh * 1024 + t) * 64 + d] = bw;
          else if (which == 1)
            o1[(bh * 1024 + t) * 64 + d] = bw;
          else
            o2[(bh * 64 + d) * 1024 + t] = bw;
        } else {
          of[(size_t)m * N + n] = val;
        }
      }
    }
  }
}

// ---------------------------------------------------------------------------
// Causal flash attention.
// Q,K: [B*H][1024][64]; VT: [B*H][64][1024]; Y: [B][1024][768] (heads merged)
// Block = (pair, h, b); q-tiles {15-pair, pair} -> uniform 17 k-tiles/block.
// Softmax in log2 domain; row-sum l via ones-column MFMA.
// ---------------------------------------------------------------------------
__global__ __launch_bounds__(256) void attn_fwd(
    const bf16_t* __restrict__ Q, const bf16_t* __restrict__ Kg,
    const bf16_t* __restrict__ VT, bf16_t* __restrict__ Y) {
  constexpr int LDA = 72;
  __shared__ __align__(16) bf16_t Ks[64][LDA];
  __shared__ __align__(16) bf16_t Vs[64][LDA];      // Vs[d][kpos]
  __shared__ __align__(16) bf16_t Ps[4][16][LDA];   // per-wave P tile

  const int tid = threadIdx.x;
  const int w = tid >> 6, lane = tid & 63;
  const int quad = lane >> 4, l16 = lane & 15;
  const int pair = blockIdx.x, h = blockIdx.y, b = blockIdx.z;
  const size_t bh = (size_t)(b * 12 + h);
  const bf16_t* Qbh = Q + bh * 1024 * 64;
  const bf16_t* Kbh = Kg + bh * 1024 * 64;
  const bf16_t* VTbh = VT + bh * 64 * 1024;

  const int srow = tid >> 2;        // 0..63
  const int scol = (tid & 3) << 4;  // 0,16,32,48
  constexpr float SC = 0.18033688011112042f;  // log2(e) / sqrt(64)

  const bf16_t one_b = (bf16_t)1.0f;
  const bf16x8 ones = {one_b, one_b, one_b, one_b,
                       one_b, one_b, one_b, one_b};

  for (int phase = 0; phase < 2; ++phase) {
    const int qt = phase ? pair : (15 - pair);  // big tile first

    const int qrow = qt * 64 + w * 16 + l16;
    bf16x8 qf0 = *(const bf16x8*)(Qbh + (size_t)qrow * 64 + quad * 8);
    bf16x8 qf1 = *(const bf16x8*)(Qbh + (size_t)qrow * 64 + 32 + quad * 8);

    float m_r[4];
    f32x4 o[5] = {};  // o[0..3]: V columns; o[4]: row-sum (l)
#pragma unroll
    for (int r = 0; r < 4; ++r) m_r[r] = -INFINITY;

    for (int kt = 0; kt <= qt; ++kt) {
      const bf16_t* kg = Kbh + (size_t)(kt * 64 + srow) * 64 + scol;
      *(float4*)(&Ks[srow][scol])     = *(const float4*)(kg);
      *(float4*)(&Ks[srow][scol + 8]) = *(const float4*)(kg + 8);
      const bf16_t* vg = VTbh + (size_t)srow * 1024 + kt * 64 + scol;
      *(float4*)(&Vs[srow][scol])     = *(const float4*)(vg);
      *(float4*)(&Vs[srow][scol + 8]) = *(const float4*)(vg + 8);
      __syncthreads();

      // S = Q * K^T
      f32x4 s[4];
#pragma unroll
      for (int ni = 0; ni < 4; ++ni) {
        bf16x8 kf0 = *(const bf16x8*)(&Ks[ni * 16 + l16][quad * 8]);
        bf16x8 kf1 = *(const bf16x8*)(&Ks[ni * 16 + l16][32 + quad * 8]);
        f32x4 t = {};
        t = MFMA16(qf0, kf0, t);
        t = MFMA16(qf1, kf1, t);
        s[ni] = t;
      }
      if (kt == qt) {
#pragma unroll
        for (int ni = 0; ni < 4; ++ni)
#pragma unroll
          for (int r = 0; r < 4; ++r) {
            const int kp = ni * 16 + l16;
            const int qr = w * 16 + quad * 4 + r;
            s[ni][r] = (kp > qr) ? -INFINITY : s[ni][r] * SC;
          }
      } else {
#pragma unroll
        for (int ni = 0; ni < 4; ++ni)
#pragma unroll
          for (int r = 0; r < 4; ++r) s[ni][r] *= SC;
      }
      float alpha[4];
#pragma unroll
      for (int r = 0; r < 4; ++r) {
        float v = fmaxf(fmaxf(s[0][r], s[1][r]), fmaxf(s[2][r], s[3][r]));
        v = fmaxf(v, __shfl_xor(v, 1));
        v = fmaxf(v, __shfl_xor(v, 2));
        v = fmaxf(v, __shfl_xor(v, 4));
        v = fmaxf(v, __shfl_xor(v, 8));
        const float mn = fmaxf(m_r[r], v);
        alpha[r] = exp2f(m_r[r] - mn);
        m_r[r] = mn;
      }
      // P -> Ps (per-wave region; intra-wave dependency only, no barrier)
#pragma unroll
      for (int ni = 0; ni < 4; ++ni)
#pragma unroll
        for (int r = 0; r < 4; ++r)
          Ps[w][quad * 4 + r][ni * 16 + l16] =
              (bf16_t)exp2f(s[ni][r] - m_r[r]);
#pragma unroll
      for (int nd = 0; nd < 5; ++nd)
#pragma unroll
        for (int r = 0; r < 4; ++r) o[nd][r] *= alpha[r];

      bf16x8 pf0 = *(const bf16x8*)(&Ps[w][l16][quad * 8]);
      bf16x8 pf1 = *(const bf16x8*)(&Ps[w][l16][32 + quad * 8]);
#pragma unroll
      for (int nd = 0; nd < 4; ++nd) {
        bf16x8 vf0 = *(const bf16x8*)(&Vs[nd * 16 + l16][quad * 8]);
        bf16x8 vf1 = *(const bf16x8*)(&Vs[nd * 16 + l16][32 + quad * 8]);
        o[nd] = MFMA16(pf0, vf0, o[nd]);
        o[nd] = MFMA16(pf1, vf1, o[nd]);
      }
      o[4] = MFMA16(pf0, ones, o[4]);
      o[4] = MFMA16(pf1, ones, o[4]);
      __syncthreads();  // Ks/Vs consumed before next staging
    }

#pragma unroll
    for (int r = 0; r < 4; ++r) {
      const float inv = 1.0f / o[4][r];
      const int t = qt * 64 + w * 16 + quad * 4 + r;
      bf16_t* yrow = Y + ((size_t)b * 1024 + t) * 768 + h * 64;
#pragma unroll
      for (int nd = 0; nd < 4; ++nd)
        yrow[nd * 16 + l16] = (bf16_t)(o[nd][r] * inv);
    }
  }
}

// ---------------------------------------------------------------------------
extern "C" void kernel_launch(void* const* d_in, const int* in_sizes, int n_in,
                              void* d_out, int out_size, void* d_ws,
                              size_t ws_size, hipStream_t stream) {
  const float* x      = (const float*)d_in[0];
  const float* W_attn = (const float*)d_in[1];
  const float* b_attn = (const float*)d_in[2];
  const float* W_proj = (const float*)d_in[3];
  const float* b_proj = (const float*)d_in[4];
  float* out = (float*)d_out;   // fp32 output per reference dtype

  const size_t HEADS = 96;  // B*H = 8*12
  bf16_t* wta = (bf16_t*)d_ws;                  // [2304][768]
  bf16_t* wtp = wta + (size_t)2304 * 768;       // [768][768]
  bf16_t* qw  = wtp + (size_t)768 * 768;        // [96][1024][64]
  bf16_t* kw  = qw + HEADS * 1024 * 64;         // [96][1024][64]
  bf16_t* vtw = kw + HEADS * 1024 * 64;         // [96][64][1024]
  bf16_t* yw  = vtw + HEADS * 1024 * 64;        // [8192][768]
  bf16_t* xb  = yw + (size_t)8192 * 768;        // [8192][768] bf16 x

  f32_to_bf16<<<dim3(8192 * 768 / (256 * 8)), 256, 0, stream>>>(x, xb);
  transpose_f32_to_bf16<<<dim3(2304 / 32, 768 / 32), 256, 0, stream>>>(
      W_attn, wta, 768, 2304);
  transpose_f32_to_bf16<<<dim3(768 / 32, 768 / 32), 256, 0, stream>>>(
      W_proj, wtp, 768, 768);
  gemm_bt<true><<<dim3(2304 / 128, 8192 / 128), 256, 0, stream>>>(
      xb, wta, b_attn, qw, kw, vtw, nullptr, 8192, 2304, 768);
  attn_fwd<<<dim3(8, 12, 8), 256, 0, stream>>>(qw, kw, vtw, yw);
  gemm_bt<false><<<dim3(768 / 128, 8192 / 128), 256, 0, stream>>>(
      yw, wtp, b_proj, nullptr, nullptr, nullptr, out, 8192, 768, 768);
}

// Round 9
// 269.731 us; speedup vs baseline: 1.1690x; 1.1690x over previous
//
#include <hip/hip_runtime.h>
#include <hip/hip_bf16.h>
#include <cmath>

typedef __bf16 bf16_t;
typedef __bf16 bf16x8 __attribute__((ext_vector_type(8)));
typedef float f32x4 __attribute__((ext_vector_type(4)));

#define MFMA16(A, B, C) __builtin_amdgcn_mfma_f32_16x16x32_bf16(A, B, C, 0, 0, 0)

// Async global->LDS DMA, 16 B per lane. LDS dest = wave-uniform base + lane*16.
#define GLOAD_LDS16(g, l)                                                      \
  __builtin_amdgcn_global_load_lds(                                            \
      (const __attribute__((address_space(1))) void*)(g),                      \
      (__attribute__((address_space(3))) void*)(l), 16, 0, 0)

// ---------------------------------------------------------------------------
// fp32 -> bf16 elementwise (x pre-convert), 8 elems/thread
// ---------------------------------------------------------------------------
__global__ __launch_bounds__(256) void f32_to_bf16(
    const float* __restrict__ src, bf16_t* __restrict__ dst) {
  const size_t i = (size_t)blockIdx.x * 256 + threadIdx.x;
  const float4 a0 = ((const float4*)src)[i * 2];
  const float4 a1 = ((const float4*)src)[i * 2 + 1];
  bf16x8 v = {(bf16_t)a0.x, (bf16_t)a0.y, (bf16_t)a0.z, (bf16_t)a0.w,
              (bf16_t)a1.x, (bf16_t)a1.y, (bf16_t)a1.z, (bf16_t)a1.w};
  ((bf16x8*)dst)[i] = v;
}

// ---------------------------------------------------------------------------
// Transpose fp32 src[R][C] -> bf16 dst[C][R]  (R, C multiples of 32)
// ---------------------------------------------------------------------------
__global__ __launch_bounds__(256) void transpose_f32_to_bf16(
    const float* __restrict__ src, bf16_t* __restrict__ dst, int R, int C) {
  __shared__ bf16_t tile[32][33];
  const int c0 = blockIdx.x * 32, r0 = blockIdx.y * 32;
  const int tr = threadIdx.x >> 5;   // 0..7
  const int tc = threadIdx.x & 31;   // 0..31
#pragma unroll
  for (int i = 0; i < 32; i += 8)
    tile[tr + i][tc] = (bf16_t)src[(size_t)(r0 + tr + i) * C + (c0 + tc)];
  __syncthreads();
#pragma unroll
  for (int i = 0; i < 32; i += 8)
    dst[(size_t)(c0 + tr + i) * R + (r0 + tc)] = tile[tc][tr + i];
}

// ---------------------------------------------------------------------------
// QKV GEMM, 256x128 block tile: q/k/v = x[M][K] * WT[N][K]^T + bias.
// Swizzled DMA staging (round-7 scheme, 0 bank conflicts), double-buffered,
// one barrier per K-iter. Waves 2x2: each computes 128(m) x 64(n) = 8x4 accs
// -> 32 MFMA + 12 ds_read_b128 per barrier (0.75x staging/FLOP vs 128^2).
// Scatter: q [B*H][T][64], k [B*H][T][64], vt [B*H][64][T].
// ---------------------------------------------------------------------------
__global__ __launch_bounds__(256) void gemm_qkv(
    const bf16_t* __restrict__ A, const bf16_t* __restrict__ BT,
    const float* __restrict__ bias,
    bf16_t* __restrict__ o0, bf16_t* __restrict__ o1, bf16_t* __restrict__ o2,
    int K) {
  constexpr int BM = 256, BN = 128, BK = 32;
  __shared__ __align__(16) bf16_t As[2][BM][BK];  // 32 KB
  __shared__ __align__(16) bf16_t Bs[2][BN][BK];  // 16 KB

  const int tid = threadIdx.x;
  const int wave = tid >> 6, lane = tid & 63;
  const int wr = wave >> 1, wc = wave & 1;
  const int quad = lane >> 4, l16 = lane & 15;
  const int mt = blockIdx.y, nt = blockIdx.x;

  // staging: lane i -> row i/4 (16-row chunks), swizzled 16B chunk
  const int rl = lane >> 2;
  const int cq = ((lane & 3) - (rl >> 1)) & 3;
  const int ac = cq << 3;
  const bf16_t* Ag[4];
#pragma unroll
  for (int j = 0; j < 4; ++j)
    Ag[j] = A + (size_t)(mt * BM + wave * 64 + j * 16 + rl) * K + ac;
  const bf16_t* Bg[2];
#pragma unroll
  for (int j = 0; j < 2; ++j)
    Bg[j] = BT + (size_t)(nt * BN + wave * 32 + j * 16 + rl) * K + ac;

  const int sw = ((quad + (l16 >> 1)) & 3) << 3;  // swizzle-corrected read

  f32x4 acc[8][4] = {};

  auto stage = [&](int k0, int buf) {
#pragma unroll
    for (int j = 0; j < 4; ++j)
      GLOAD_LDS16(Ag[j] + k0, &As[buf][wave * 64 + j * 16][0]);
#pragma unroll
    for (int j = 0; j < 2; ++j)
      GLOAD_LDS16(Bg[j] + k0, &Bs[buf][wave * 32 + j * 16][0]);
  };
  auto compute = [&](int buf) {
    bf16x8 bfr[4];
#pragma unroll
    for (int ni = 0; ni < 4; ++ni)
      bfr[ni] = *(const bf16x8*)(&Bs[buf][wc * 64 + ni * 16 + l16][sw]);
#pragma unroll
    for (int mi = 0; mi < 8; ++mi) {
      bf16x8 af = *(const bf16x8*)(&As[buf][wr * 128 + mi * 16 + l16][sw]);
#pragma unroll
      for (int ni = 0; ni < 4; ++ni)
        acc[mi][ni] = MFMA16(af, bfr[ni], acc[mi][ni]);
    }
  };

  const int NIT = K / BK;  // 24
  stage(0, 0);
  for (int k = 0; k + 2 < NIT; k += 2) {
    __syncthreads();
    stage((k + 1) * BK, 1);
    compute(0);
    __syncthreads();
    stage((k + 2) * BK, 0);
    compute(1);
  }
  __syncthreads();
  stage((NIT - 1) * BK, 1);
  compute(0);
  __syncthreads();
  compute(1);

  // Epilogue. C/D layout: col = l16 (n), row = quad*4 + r (m).
  const int m_base = mt * BM + wr * 128;
  const int n_base = nt * BN + wc * 64;
#pragma unroll
  for (int ni = 0; ni < 4; ++ni) {
    const int n = n_base + ni * 16 + l16;
    const float bv = bias[n];
    const int which = n / 768;
    const int c = n - which * 768;
    const int h = c >> 6, d = c & 63;
#pragma unroll
    for (int mi = 0; mi < 8; ++mi) {
#pragma unroll
      for (int r = 0; r < 4; ++r) {
        const int m = m_base + mi * 16 + quad * 4 + r;
        const bf16_t bw = (bf16_t)(acc[mi][ni][r] + bv);
        const int b = m >> 10, t = m & 1023;
        const size_t bh = (size_t)(b * 12 + h);
        if (which == 0)
          o0[(bh * 1024 + t) * 64 + d] = bw;
        else if (which == 1)
          o1[(bh * 1024 + t) * 64 + d] = bw;
        else
          o2[(bh * 64 + d) * 1024 + t] = bw;
      }
    }
  }
}

// ---------------------------------------------------------------------------
// Proj GEMM (round-7 structure): of[M][N] = A[M][K] * BT[N][K]^T + bias.
// 128x128 tile, swizzled DMA staging, double-buffered, fp32 out.
// ---------------------------------------------------------------------------
__global__ __launch_bounds__(256) void gemm_proj(
    const bf16_t* __restrict__ A, const bf16_t* __restrict__ BT,
    const float* __restrict__ bias, float* __restrict__ of, int N, int K) {
  constexpr int BM = 128, BN = 128, BK = 32;
  __shared__ __align__(16) bf16_t As[2][BM][BK];
  __shared__ __align__(16) bf16_t Bs[2][BN][BK];

  const int tid = threadIdx.x;
  const int wave = tid >> 6, lane = tid & 63;
  const int wr = wave >> 1, wc = wave & 1;
  const int quad = lane >> 4, l16 = lane & 15;
  const int mt = blockIdx.y, nt = blockIdx.x;

  const int rl = lane >> 2;
  const int cq = ((lane & 3) - (rl >> 1)) & 3;
  const int ac = cq << 3;
  const bf16_t* Ag0 = A + (size_t)(mt * BM + wave * 32 + rl) * K + ac;
  const bf16_t* Ag1 = Ag0 + (size_t)16 * K;
  const bf16_t* Bg0 = BT + (size_t)(nt * BN + wave * 32 + rl) * K + ac;
  const bf16_t* Bg1 = Bg0 + (size_t)16 * K;

  const int sw = ((quad + (l16 >> 1)) & 3) << 3;

  f32x4 acc[4][4] = {};

  auto stage = [&](int k0, int buf) {
    GLOAD_LDS16(Ag0 + k0, &As[buf][wave * 32][0]);
    GLOAD_LDS16(Ag1 + k0, &As[buf][wave * 32 + 16][0]);
    GLOAD_LDS16(Bg0 + k0, &Bs[buf][wave * 32][0]);
    GLOAD_LDS16(Bg1 + k0, &Bs[buf][wave * 32 + 16][0]);
  };
  auto compute = [&](int buf) {
    bf16x8 af[4], bfr[4];
#pragma unroll
    for (int mi = 0; mi < 4; ++mi)
      af[mi] = *(const bf16x8*)(&As[buf][wr * 64 + mi * 16 + l16][sw]);
#pragma unroll
    for (int ni = 0; ni < 4; ++ni)
      bfr[ni] = *(const bf16x8*)(&Bs[buf][wc * 64 + ni * 16 + l16][sw]);
#pragma unroll
    for (int mi = 0; mi < 4; ++mi)
#pragma unroll
      for (int ni = 0; ni < 4; ++ni)
        acc[mi][ni] = MFMA16(af[mi], bfr[ni], acc[mi][ni]);
  };

  const int NIT = K / BK;  // 24
  stage(0, 0);
  for (int k = 0; k + 2 < NIT; k += 2) {
    __syncthreads();
    stage((k + 1) * BK, 1);
    compute(0);
    __syncthreads();
    stage((k + 2) * BK, 0);
    compute(1);
  }
  __syncthreads();
  stage((NIT - 1) * BK, 1);
  compute(0);
  __syncthreads();
  compute(1);

  const int m_base = mt * BM + wr * 64;
  const int n_base = nt * BN + wc * 64;
#pragma unroll
  for (int ni = 0; ni < 4; ++ni) {
    const int n = n_base + ni * 16 + l16;
    const float bv = bias[n];
#pragma unroll
    for (int mi = 0; mi < 4; ++mi)
#pragma unroll
      for (int r = 0; r < 4; ++r) {
        const int m = m_base + mi * 16 + quad * 4 + r;
        of[(size_t)m * N + n] = acc[mi][ni][r] + bv;
      }
  }
}

// ---------------------------------------------------------------------------
// Causal flash attention, 128 q-rows per block (each wave 32 rows, 2 m-frags).
// Q,K: [B*H][1024][64]; VT: [B*H][64][1024]; Y: [B][1024][768].
// Block = (pair, h, b); q-tiles {7-pair, pair} -> uniform 18 k-iters/block.
// K/V staging, barriers, Vs frag reads amortized 2x vs 64-row blocks.
// Softmax in log2 domain; row-sum l via ones-column MFMA.
// ---------------------------------------------------------------------------
__global__ __launch_bounds__(256) void attn_fwd(
    const bf16_t* __restrict__ Q, const bf16_t* __restrict__ Kg,
    const bf16_t* __restrict__ VT, bf16_t* __restrict__ Y) {
  constexpr int LDA = 72;
  __shared__ __align__(16) bf16_t Ks[64][LDA];
  __shared__ __align__(16) bf16_t Vs[64][LDA];      // Vs[d][kpos]
  __shared__ __align__(16) bf16_t Ps[4][32][LDA];   // per-wave P tile (32 q)

  const int tid = threadIdx.x;
  const int w = tid >> 6, lane = tid & 63;
  const int quad = lane >> 4, l16 = lane & 15;
  const int pair = blockIdx.x, h = blockIdx.y, b = blockIdx.z;
  const size_t bh = (size_t)(b * 12 + h);
  const bf16_t* Qbh = Q + bh * 1024 * 64;
  const bf16_t* Kbh = Kg + bh * 1024 * 64;
  const bf16_t* VTbh = VT + bh * 64 * 1024;

  const int srow = tid >> 2;        // 0..63
  const int scol = (tid & 3) << 4;  // 0,16,32,48
  constexpr float SC = 0.18033688011112042f;  // log2(e) / sqrt(64)

  const bf16_t one_b = (bf16_t)1.0f;
  const bf16x8 ones = {one_b, one_b, one_b, one_b,
                       one_b, one_b, one_b, one_b};

  for (int phase = 0; phase < 2; ++phase) {
    const int qt = phase ? pair : (7 - pair);  // big tile first

    // Q A-frags for 2 m-tiles: rows qt*128 + w*32 + mi*16 + l16
    bf16x8 qf[2][2];
#pragma unroll
    for (int mi = 0; mi < 2; ++mi) {
      const int qrow = qt * 128 + w * 32 + mi * 16 + l16;
      qf[mi][0] = *(const bf16x8*)(Qbh + (size_t)qrow * 64 + quad * 8);
      qf[mi][1] = *(const bf16x8*)(Qbh + (size_t)qrow * 64 + 32 + quad * 8);
    }

    float m_r[2][4];
    f32x4 o[2][5] = {};  // per m-frag: 4 V cols + row-sum
#pragma unroll
    for (int mi = 0; mi < 2; ++mi)
#pragma unroll
      for (int r = 0; r < 4; ++r) m_r[mi][r] = -INFINITY;

    const int nkt = 2 * qt + 2;
    for (int kt = 0; kt < nkt; ++kt) {
      const bf16_t* kg = Kbh + (size_t)(kt * 64 + srow) * 64 + scol;
      *(float4*)(&Ks[srow][scol])     = *(const float4*)(kg);
      *(float4*)(&Ks[srow][scol + 8]) = *(const float4*)(kg + 8);
      const bf16_t* vg = VTbh + (size_t)srow * 1024 + kt * 64 + scol;
      *(float4*)(&Vs[srow][scol])     = *(const float4*)(vg);
      *(float4*)(&Vs[srow][scol + 8]) = *(const float4*)(vg + 8);
      __syncthreads();

      // S = Q * K^T  (2 m-frags share each K fragment)
      f32x4 s[2][4];
#pragma unroll
      for (int ni = 0; ni < 4; ++ni) {
        bf16x8 kf0 = *(const bf16x8*)(&Ks[ni * 16 + l16][quad * 8]);
        bf16x8 kf1 = *(const bf16x8*)(&Ks[ni * 16 + l16][32 + quad * 8]);
#pragma unroll
        for (int mi = 0; mi < 2; ++mi) {
          f32x4 t = {};
          t = MFMA16(qf[mi][0], kf0, t);
          t = MFMA16(qf[mi][1], kf1, t);
          s[mi][ni] = t;
        }
      }
      if (kt >= 2 * qt) {  // last two k-tiles: causal mask
#pragma unroll
        for (int mi = 0; mi < 2; ++mi)
#pragma unroll
          for (int ni = 0; ni < 4; ++ni)
#pragma unroll
            for (int r = 0; r < 4; ++r) {
              const int kp = kt * 64 + ni * 16 + l16;
              const int qr = qt * 128 + w * 32 + mi * 16 + quad * 4 + r;
              s[mi][ni][r] = (kp > qr) ? -INFINITY : s[mi][ni][r] * SC;
            }
      } else {
#pragma unroll
        for (int mi = 0; mi < 2; ++mi)
#pragma unroll
          for (int ni = 0; ni < 4; ++ni)
#pragma unroll
            for (int r = 0; r < 4; ++r) s[mi][ni][r] *= SC;
      }
#pragma unroll
      for (int mi = 0; mi < 2; ++mi) {
        float alpha[4];
#pragma unroll
        for (int r = 0; r < 4; ++r) {
          float v = fmaxf(fmaxf(s[mi][0][r], s[mi][1][r]),
                          fmaxf(s[mi][2][r], s[mi][3][r]));
          v = fmaxf(v, __shfl_xor(v, 1));
          v = fmaxf(v, __shfl_xor(v, 2));
          v = fmaxf(v, __shfl_xor(v, 4));
          v = fmaxf(v, __shfl_xor(v, 8));
          const float mn = fmaxf(m_r[mi][r], v);
          alpha[r] = exp2f(m_r[mi][r] - mn);
          m_r[mi][r] = mn;
        }
        // P -> Ps (per-wave region; intra-wave dependency only)
#pragma unroll
        for (int ni = 0; ni < 4; ++ni)
#pragma unroll
          for (int r = 0; r < 4; ++r)
            Ps[w][mi * 16 + quad * 4 + r][ni * 16 + l16] =
                (bf16_t)exp2f(s[mi][ni][r] - m_r[mi][r]);
#pragma unroll
        for (int nd = 0; nd < 5; ++nd)
#pragma unroll
          for (int r = 0; r < 4; ++r) o[mi][nd][r] *= alpha[r];
      }

      bf16x8 pf[2][2];
#pragma unroll
      for (int mi = 0; mi < 2; ++mi) {
        pf[mi][0] = *(const bf16x8*)(&Ps[w][mi * 16 + l16][quad * 8]);
        pf[mi][1] = *(const bf16x8*)(&Ps[w][mi * 16 + l16][32 + quad * 8]);
      }
#pragma unroll
      for (int nd = 0; nd < 4; ++nd) {
        bf16x8 vf0 = *(const bf16x8*)(&Vs[nd * 16 + l16][quad * 8]);
        bf16x8 vf1 = *(const bf16x8*)(&Vs[nd * 16 + l16][32 + quad * 8]);
#pragma unroll
        for (int mi = 0; mi < 2; ++mi) {
          o[mi][nd] = MFMA16(pf[mi][0], vf0, o[mi][nd]);
          o[mi][nd] = MFMA16(pf[mi][1], vf1, o[mi][nd]);
        }
      }
#pragma unroll
      for (int mi = 0; mi < 2; ++mi) {
        o[mi][4] = MFMA16(pf[mi][0], ones, o[mi][4]);
        o[mi][4] = MFMA16(pf[mi][1], ones, o[mi][4]);
      }
      __syncthreads();  // Ks/Vs consumed before next staging
    }

#pragma unroll
    for (int mi = 0; mi < 2; ++mi)
#pragma unroll
      for (int r = 0; r < 4; ++r) {
        const float inv = 1.0f / o[mi][4][r];
        const int t = qt * 128 + w * 32 + mi * 16 + quad * 4 + r;
        bf16_t* yrow = Y + ((size_t)b * 1024 + t) * 768 + h * 64;
#pragma unroll
        for (int nd = 0; nd < 4; ++nd)
          yrow[nd * 16 + l16] = (bf16_t)(o[mi][nd][r] * inv);
      }
  }
}

// ---------------------------------------------------------------------------
extern "C" void kernel_launch(void* const* d_in, const int* in_sizes, int n_in,
                              void* d_out, int out_size, void* d_ws,
                              size_t ws_size, hipStream_t stream) {
  const float* x      = (const float*)d_in[0];
  const float* W_attn = (const float*)d_in[1];
  const float* b_attn = (const float*)d_in[2];
  const float* W_proj = (const float*)d_in[3];
  const float* b_proj = (const float*)d_in[4];
  float* out = (float*)d_out;   // fp32 output per reference dtype

  const size_t HEADS = 96;  // B*H = 8*12
  bf16_t* wta = (bf16_t*)d_ws;                  // [2304][768]
  bf16_t* wtp = wta + (size_t)2304 * 768;       // [768][768]
  bf16_t* qw  = wtp + (size_t)768 * 768;        // [96][1024][64]
  bf16_t* kw  = qw + HEADS * 1024 * 64;         // [96][1024][64]
  bf16_t* vtw = kw + HEADS * 1024 * 64;         // [96][64][1024]
  bf16_t* yw  = vtw + HEADS * 1024 * 64;        // [8192][768]
  bf16_t* xb  = yw + (size_t)8192 * 768;        // [8192][768] bf16 x

  f32_to_bf16<<<dim3(8192 * 768 / (256 * 8)), 256, 0, stream>>>(x, xb);
  transpose_f32_to_bf16<<<dim3(2304 / 32, 768 / 32), 256, 0, stream>>>(
      W_attn, wta, 768, 2304);
  transpose_f32_to_bf16<<<dim3(768 / 32, 768 / 32), 256, 0, stream>>>(
      W_proj, wtp, 768, 768);
  gemm_qkv<<<dim3(2304 / 128, 8192 / 256), 256, 0, stream>>>(
      xb, wta, b_attn, qw, kw, vtw, 768);
  attn_fwd<<<dim3(4, 12, 8), 256, 0, stream>>>(qw, kw, vtw, yw);
  gemm_proj<<<dim3(768 / 128, 8192 / 128), 256, 0, stream>>>(
      yw, wtp, b_proj, out, 768, 768);
}

// Round 10
// 229.992 us; speedup vs baseline: 1.3709x; 1.1728x over previous
//
#include <hip/hip_runtime.h>
#include <hip/hip_bf16.h>
#include <cmath>

typedef __bf16 bf16_t;
typedef __bf16 bf16x8 __attribute__((ext_vector_type(8)));
typedef float f32x4 __attribute__((ext_vector_type(4)));

#define MFMA16(A, B, C) __builtin_amdgcn_mfma_f32_16x16x32_bf16(A, B, C, 0, 0, 0)

// Async global->LDS DMA, 16 B per lane. LDS dest = wave-uniform base + lane*16.
#define GLOAD_LDS16(g, l)                                                      \
  __builtin_amdgcn_global_load_lds(                                            \
      (const __attribute__((address_space(1))) void*)(g),                      \
      (__attribute__((address_space(3))) void*)(l), 16, 0, 0)

// ---------------------------------------------------------------------------
// fp32 -> bf16 elementwise (x pre-convert), 8 elems/thread
// ---------------------------------------------------------------------------
__global__ __launch_bounds__(256) void f32_to_bf16(
    const float* __restrict__ src, bf16_t* __restrict__ dst) {
  const size_t i = (size_t)blockIdx.x * 256 + threadIdx.x;
  const float4 a0 = ((const float4*)src)[i * 2];
  const float4 a1 = ((const float4*)src)[i * 2 + 1];
  bf16x8 v = {(bf16_t)a0.x, (bf16_t)a0.y, (bf16_t)a0.z, (bf16_t)a0.w,
              (bf16_t)a1.x, (bf16_t)a1.y, (bf16_t)a1.z, (bf16_t)a1.w};
  ((bf16x8*)dst)[i] = v;
}

// ---------------------------------------------------------------------------
// Transpose fp32 src[R][C] -> bf16 dst[C][R]  (R, C multiples of 32)
// ---------------------------------------------------------------------------
__global__ __launch_bounds__(256) void transpose_f32_to_bf16(
    const float* __restrict__ src, bf16_t* __restrict__ dst, int R, int C) {
  __shared__ bf16_t tile[32][33];
  const int c0 = blockIdx.x * 32, r0 = blockIdx.y * 32;
  const int tr = threadIdx.x >> 5;   // 0..7
  const int tc = threadIdx.x & 31;   // 0..31
#pragma unroll
  for (int i = 0; i < 32; i += 8)
    tile[tr + i][tc] = (bf16_t)src[(size_t)(r0 + tr + i) * C + (c0 + tc)];
  __syncthreads();
#pragma unroll
  for (int i = 0; i < 32; i += 8)
    dst[(size_t)(c0 + tr + i) * R + (r0 + tc)] = tile[tc][tr + i];
}

// ---------------------------------------------------------------------------
// QKV GEMM (round-7 verified structure): 128x128 tile, swizzled DMA staging,
// double-buffered, 1 barrier/K-iter. Scatter: q/k [B*H][T][64], vt [B*H][64][T]
// ---------------------------------------------------------------------------
__global__ __launch_bounds__(256) void gemm_qkv(
    const bf16_t* __restrict__ A, const bf16_t* __restrict__ BT,
    const float* __restrict__ bias,
    bf16_t* __restrict__ o0, bf16_t* __restrict__ o1, bf16_t* __restrict__ o2,
    int K) {
  constexpr int BM = 128, BN = 128, BK = 32;
  __shared__ __align__(16) bf16_t As[2][BM][BK];
  __shared__ __align__(16) bf16_t Bs[2][BN][BK];

  const int tid = threadIdx.x;
  const int wave = tid >> 6, lane = tid & 63;
  const int wr = wave >> 1, wc = wave & 1;
  const int quad = lane >> 4, l16 = lane & 15;
  const int mt = blockIdx.y, nt = blockIdx.x;

  const int rl = lane >> 2;                     // row within 16-row chunk
  const int cq = ((lane & 3) - (rl >> 1)) & 3;  // swizzled 16B chunk to fetch
  const int ac = cq << 3;
  const bf16_t* Ag0 = A + (size_t)(mt * BM + wave * 32 + rl) * K + ac;
  const bf16_t* Ag1 = Ag0 + (size_t)16 * K;
  const bf16_t* Bg0 = BT + (size_t)(nt * BN + wave * 32 + rl) * K + ac;
  const bf16_t* Bg1 = Bg0 + (size_t)16 * K;

  const int sw = ((quad + (l16 >> 1)) & 3) << 3;  // swizzle-corrected read

  f32x4 acc[4][4] = {};

  auto stage = [&](int k0, int buf) {
    GLOAD_LDS16(Ag0 + k0, &As[buf][wave * 32][0]);
    GLOAD_LDS16(Ag1 + k0, &As[buf][wave * 32 + 16][0]);
    GLOAD_LDS16(Bg0 + k0, &Bs[buf][wave * 32][0]);
    GLOAD_LDS16(Bg1 + k0, &Bs[buf][wave * 32 + 16][0]);
  };
  auto compute = [&](int buf) {
    bf16x8 af[4], bfr[4];
#pragma unroll
    for (int mi = 0; mi < 4; ++mi)
      af[mi] = *(const bf16x8*)(&As[buf][wr * 64 + mi * 16 + l16][sw]);
#pragma unroll
    for (int ni = 0; ni < 4; ++ni)
      bfr[ni] = *(const bf16x8*)(&Bs[buf][wc * 64 + ni * 16 + l16][sw]);
#pragma unroll
    for (int mi = 0; mi < 4; ++mi)
#pragma unroll
      for (int ni = 0; ni < 4; ++ni)
        acc[mi][ni] = MFMA16(af[mi], bfr[ni], acc[mi][ni]);
  };

  const int NIT = K / BK;  // 24
  stage(0, 0);
  for (int k = 0; k + 2 < NIT; k += 2) {
    __syncthreads();
    stage((k + 1) * BK, 1);
    compute(0);
    __syncthreads();
    stage((k + 2) * BK, 0);
    compute(1);
  }
  __syncthreads();
  stage((NIT - 1) * BK, 1);
  compute(0);
  __syncthreads();
  compute(1);

  // Epilogue. C/D layout: col = l16 (n), row = quad*4 + r (m).
  const int m_base = mt * BM + wr * 64;
  const int n_base = nt * BN + wc * 64;
#pragma unroll
  for (int ni = 0; ni < 4; ++ni) {
    const int n = n_base + ni * 16 + l16;
    const float bv = bias[n];
    const int which = n / 768;
    const int c = n - which * 768;
    const int h = c >> 6, d = c & 63;
#pragma unroll
    for (int mi = 0; mi < 4; ++mi) {
#pragma unroll
      for (int r = 0; r < 4; ++r) {
        const int m = m_base + mi * 16 + quad * 4 + r;
        const bf16_t bw = (bf16_t)(acc[mi][ni][r] + bv);
        const int b = m >> 10, t = m & 1023;
        const size_t bh = (size_t)(b * 12 + h);
        if (which == 0)
          o0[(bh * 1024 + t) * 64 + d] = bw;
        else if (which == 1)
          o1[(bh * 1024 + t) * 64 + d] = bw;
        else
          o2[(bh * 64 + d) * 1024 + t] = bw;
      }
    }
  }
}

// ---------------------------------------------------------------------------
// Proj GEMM (round-7 verified structure): of[M][N] = A*BT^T + bias, fp32 out.
// ---------------------------------------------------------------------------
__global__ __launch_bounds__(256) void gemm_proj(
    const bf16_t* __restrict__ A, const bf16_t* __restrict__ BT,
    const float* __restrict__ bias, float* __restrict__ of, int N, int K) {
  constexpr int BM = 128, BN = 128, BK = 32;
  __shared__ __align__(16) bf16_t As[2][BM][BK];
  __shared__ __align__(16) bf16_t Bs[2][BN][BK];

  const int tid = threadIdx.x;
  const int wave = tid >> 6, lane = tid & 63;
  const int wr = wave >> 1, wc = wave & 1;
  const int quad = lane >> 4, l16 = lane & 15;
  const int mt = blockIdx.y, nt = blockIdx.x;

  const int rl = lane >> 2;
  const int cq = ((lane & 3) - (rl >> 1)) & 3;
  const int ac = cq << 3;
  const bf16_t* Ag0 = A + (size_t)(mt * BM + wave * 32 + rl) * K + ac;
  const bf16_t* Ag1 = Ag0 + (size_t)16 * K;
  const bf16_t* Bg0 = BT + (size_t)(nt * BN + wave * 32 + rl) * K + ac;
  const bf16_t* Bg1 = Bg0 + (size_t)16 * K;

  const int sw = ((quad + (l16 >> 1)) & 3) << 3;

  f32x4 acc[4][4] = {};

  auto stage = [&](int k0, int buf) {
    GLOAD_LDS16(Ag0 + k0, &As[buf][wave * 32][0]);
    GLOAD_LDS16(Ag1 + k0, &As[buf][wave * 32 + 16][0]);
    GLOAD_LDS16(Bg0 + k0, &Bs[buf][wave * 32][0]);
    GLOAD_LDS16(Bg1 + k0, &Bs[buf][wave * 32 + 16][0]);
  };
  auto compute = [&](int buf) {
    bf16x8 af[4], bfr[4];
#pragma unroll
    for (int mi = 0; mi < 4; ++mi)
      af[mi] = *(const bf16x8*)(&As[buf][wr * 64 + mi * 16 + l16][sw]);
#pragma unroll
    for (int ni = 0; ni < 4; ++ni)
      bfr[ni] = *(const bf16x8*)(&Bs[buf][wc * 64 + ni * 16 + l16][sw]);
#pragma unroll
    for (int mi = 0; mi < 4; ++mi)
#pragma unroll
      for (int ni = 0; ni < 4; ++ni)
        acc[mi][ni] = MFMA16(af[mi], bfr[ni], acc[mi][ni]);
  };

  const int NIT = K / BK;  // 24
  stage(0, 0);
  for (int k = 0; k + 2 < NIT; k += 2) {
    __syncthreads();
    stage((k + 1) * BK, 1);
    compute(0);
    __syncthreads();
    stage((k + 2) * BK, 0);
    compute(1);
  }
  __syncthreads();
  stage((NIT - 1) * BK, 1);
  compute(0);
  __syncthreads();
  compute(1);

  const int m_base = mt * BM + wr * 64;
  const int n_base = nt * BN + wc * 64;
#pragma unroll
  for (int ni = 0; ni < 4; ++ni) {
    const int n = n_base + ni * 16 + l16;
    const float bv = bias[n];
#pragma unroll
    for (int mi = 0; mi < 4; ++mi)
#pragma unroll
      for (int r = 0; r < 4; ++r) {
        const int m = m_base + mi * 16 + quad * 4 + r;
        of[(size_t)m * N + n] = acc[mi][ni][r] + bv;
      }
  }
}

// ---------------------------------------------------------------------------
// Causal flash attention, DMA-staged K/V, double-buffered, ONE barrier/tile.
// Q,K: [B*H][1024][64]; VT: [B*H][64][1024]; Y: [B][1024][768].
// Block = (pair, h, b); q-tiles {15-pair, pair} -> uniform 17 k-iters.
// K/V LDS tiles are unpadded [64][64] with XOR chunk swizzle:
//   slot(row r, chunk c) = (c + (r&7)) & 7  -> frag reads 2-way (free);
//   DMA lane fetches chunk ((lane&7) - (lane>>3)) & 7 of row lane>>3.
// Next tile's DMA issued right after the barrier -> full compute phase of
// latency hiding. Softmax log2-domain; row-sum via ones-column MFMA.
// ---------------------------------------------------------------------------
__global__ __launch_bounds__(256) void attn_fwd(
    const bf16_t* __restrict__ Q, const bf16_t* __restrict__ Kg,
    const bf16_t* __restrict__ VT, bf16_t* __restrict__ Y) {
  __shared__ __align__(16) bf16_t Ks[2][64][64];  // 16 KB
  __shared__ __align__(16) bf16_t Vs[2][64][64];  // 16 KB  (row = d)
  __shared__ __align__(16) bf16_t Ps[4][16][72];  // 9 KB, padded (VALU-written)

  const int tid = threadIdx.x;
  const int w = tid >> 6, lane = tid & 63;
  const int quad = lane >> 4, l16 = lane & 15;
  const int pair = blockIdx.x, h = blockIdx.y, b = blockIdx.z;
  const size_t bh = (size_t)(b * 12 + h);
  const bf16_t* Qbh = Q + bh * 65536;
  const bf16_t* Kbh = Kg + bh * 65536;
  const bf16_t* VTbh = VT + bh * 65536;

  // DMA fetch mapping: lane -> row lane>>3 (of an 8-row group), slot lane&7,
  // fetches global chunk (slot - row)&7 so that slot = (chunk + row)&7.
  const int drow = lane >> 3;
  const int dchunk = (((lane & 7) - drow) & 7) << 3;  // element offset

  // swizzle-corrected fragment read offsets (rows base+l16, base%16==0)
  const int so0 = ((quad + (l16 & 7)) & 7) << 3;
  const int so1 = so0 ^ 32;

  constexpr float SC = 0.18033688011112042f;  // log2(e) / sqrt(64)
  const bf16_t one_b = (bf16_t)1.0f;
  const bf16x8 ones = {one_b, one_b, one_b, one_b,
                       one_b, one_b, one_b, one_b};

  auto stageKV = [&](int kt, int bufi) {
#pragma unroll
    for (int j = 0; j < 2; ++j) {
      const int r = w * 16 + j * 8 + drow;
      GLOAD_LDS16(Kbh + (size_t)(kt * 64 + r) * 64 + dchunk,
                  &Ks[bufi][w * 16 + j * 8][0]);
      GLOAD_LDS16(VTbh + (size_t)r * 1024 + kt * 64 + dchunk,
                  &Vs[bufi][w * 16 + j * 8][0]);
    }
  };

  for (int phase = 0; phase < 2; ++phase) {
    const int qt = phase ? pair : (15 - pair);  // big tile first

    const int qrow = qt * 64 + w * 16 + l16;
    bf16x8 qf0 = *(const bf16x8*)(Qbh + (size_t)qrow * 64 + quad * 8);
    bf16x8 qf1 = *(const bf16x8*)(Qbh + (size_t)qrow * 64 + 32 + quad * 8);

    float m_r[4];
    f32x4 o[5] = {};  // o[0..3]: V columns; o[4]: row-sum (l)
#pragma unroll
    for (int r = 0; r < 4; ++r) m_r[r] = -INFINITY;

    __syncthreads();  // all waves done reading prev-phase LDS
    stageKV(0, 0);
    int buf = 0;
    for (int kt = 0; kt <= qt; ++kt) {
      __syncthreads();  // DMA(kt) landed; prior reads of buf^1 done
      if (kt < qt) stageKV(kt + 1, buf ^ 1);

      // S = Q * K^T
      f32x4 s[4];
#pragma unroll
      for (int ni = 0; ni < 4; ++ni) {
        bf16x8 kf0 = *(const bf16x8*)(&Ks[buf][ni * 16 + l16][so0]);
        bf16x8 kf1 = *(const bf16x8*)(&Ks[buf][ni * 16 + l16][so1]);
        f32x4 t = {};
        t = MFMA16(qf0, kf0, t);
        t = MFMA16(qf1, kf1, t);
        s[ni] = t;
      }
      if (kt == qt) {
#pragma unroll
        for (int ni = 0; ni < 4; ++ni)
#pragma unroll
          for (int r = 0; r < 4; ++r) {
            const int kp = ni * 16 + l16;
            const int qr = w * 16 + quad * 4 + r;
            s[ni][r] = (kp > qr) ? -INFINITY : s[ni][r] * SC;
          }
      } else {
#pragma unroll
        for (int ni = 0; ni < 4; ++ni)
#pragma unroll
          for (int r = 0; r < 4; ++r) s[ni][r] *= SC;
      }
      float alpha[4];
#pragma unroll
      for (int r = 0; r < 4; ++r) {
        float v = fmaxf(fmaxf(s[0][r], s[1][r]), fmaxf(s[2][r], s[3][r]));
        v = fmaxf(v, __shfl_xor(v, 1));
        v = fmaxf(v, __shfl_xor(v, 2));
        v = fmaxf(v, __shfl_xor(v, 4));
        v = fmaxf(v, __shfl_xor(v, 8));
        const float mn = fmaxf(m_r[r], v);
        alpha[r] = exp2f(m_r[r] - mn);
        m_r[r] = mn;
      }
      // P -> Ps (per-wave region; intra-wave dependency only, no barrier)
#pragma unroll
      for (int ni = 0; ni < 4; ++ni)
#pragma unroll
        for (int r = 0; r < 4; ++r)
          Ps[w][quad * 4 + r][ni * 16 + l16] =
              (bf16_t)exp2f(s[ni][r] - m_r[r]);
#pragma unroll
      for (int nd = 0; nd < 5; ++nd)
#pragma unroll
        for (int r = 0; r < 4; ++r) o[nd][r] *= alpha[r];

      bf16x8 pf0 = *(const bf16x8*)(&Ps[w][l16][quad * 8]);
      bf16x8 pf1 = *(const bf16x8*)(&Ps[w][l16][32 + quad * 8]);
#pragma unroll
      for (int nd = 0; nd < 4; ++nd) {
        bf16x8 vf0 = *(const bf16x8*)(&Vs[buf][nd * 16 + l16][so0]);
        bf16x8 vf1 = *(const bf16x8*)(&Vs[buf][nd * 16 + l16][so1]);
        o[nd] = MFMA16(pf0, vf0, o[nd]);
        o[nd] = MFMA16(pf1, vf1, o[nd]);
      }
      o[4] = MFMA16(pf0, ones, o[4]);
      o[4] = MFMA16(pf1, ones, o[4]);
      buf ^= 1;
    }

#pragma unroll
    for (int r = 0; r < 4; ++r) {
      const float inv = 1.0f / o[4][r];
      const int t = qt * 64 + w * 16 + quad * 4 + r;
      bf16_t* yrow = Y + ((size_t)b * 1024 + t) * 768 + h * 64;
#pragma unroll
      for (int nd = 0; nd < 4; ++nd)
        yrow[nd * 16 + l16] = (bf16_t)(o[nd][r] * inv);
    }
  }
}

// ---------------------------------------------------------------------------
extern "C" void kernel_launch(void* const* d_in, const int* in_sizes, int n_in,
                              void* d_out, int out_size, void* d_ws,
                              size_t ws_size, hipStream_t stream) {
  const float* x      = (const float*)d_in[0];
  const float* W_attn = (const float*)d_in[1];
  const float* b_attn = (const float*)d_in[2];
  const float* W_proj = (const float*)d_in[3];
  const float* b_proj = (const float*)d_in[4];
  float* out = (float*)d_out;   // fp32 output per reference dtype

  const size_t HEADS = 96;  // B*H = 8*12
  bf16_t* wta = (bf16_t*)d_ws;                  // [2304][768]
  bf16_t* wtp = wta + (size_t)2304 * 768;       // [768][768]
  bf16_t* qw  = wtp + (size_t)768 * 768;        // [96][1024][64]
  bf16_t* kw  = qw + HEADS * 1024 * 64;         // [96][1024][64]
  bf16_t* vtw = kw + HEADS * 1024 * 64;         // [96][64][1024]
  bf16_t* yw  = vtw + HEADS * 1024 * 64;        // [8192][768]
  bf16_t* xb  = yw + (size_t)8192 * 768;        // [8192][768] bf16 x

  f32_to_bf16<<<dim3(8192 * 768 / (256 * 8)), 256, 0, stream>>>(x, xb);
  transpose_f32_to_bf16<<<dim3(2304 / 32, 768 / 32), 256, 0, stream>>>(
      W_attn, wta, 768, 2304);
  transpose_f32_to_bf16<<<dim3(768 / 32, 768 / 32), 256, 0, stream>>>(
      W_proj, wtp, 768, 768);
  gemm_qkv<<<dim3(2304 / 128, 8192 / 128), 256, 0, stream>>>(
      xb, wta, b_attn, qw, kw, vtw, 768);
  attn_fwd<<<dim3(8, 12, 8), 256, 0, stream>>>(qw, kw, vtw, yw);
  gemm_proj<<<dim3(768 / 128, 8192 / 128), 256, 0, stream>>>(
      yw, wtp, b_proj, out, 768, 768);
}